// Round 1
// baseline (525.643 us; speedup 1.0000x reference)
//
#include <hip/hip_runtime.h>
#include <hip/hip_bf16.h>

#define NN 50000
#define DD 128
#define EE 600000

// ---------------- CSR build ----------------

__global__ void count_edges(const int* __restrict__ tgt, int* __restrict__ cnt, int e) {
    for (int i = blockIdx.x * blockDim.x + threadIdx.x; i < e; i += gridDim.x * blockDim.x)
        atomicAdd(&cnt[tgt[i]], 1);
}

// single-block exclusive scan: reads cnt_pos (counts), writes off[0..n] and
// rewrites cnt_pos[i] = exclusive prefix (cursor start for fill).
__global__ __launch_bounds__(1024) void scan_excl(int* __restrict__ cnt_pos, int* __restrict__ off, int n) {
    __shared__ int sd[1024];
    int tid = threadIdx.x;
    int carry = 0;
    for (int base = 0; base < n; base += 4096) {
        int v[4];
        int loc = 0;
        int i0 = base + tid * 4;
#pragma unroll
        for (int j = 0; j < 4; ++j) {
            int idx = i0 + j;
            int c = (idx < n) ? cnt_pos[idx] : 0;
            v[j] = c;
            loc += c;
        }
        __syncthreads();           // protect sd from previous iteration's readers
        sd[tid] = loc;
        __syncthreads();
        for (int s = 1; s < 1024; s <<= 1) {
            int add = (tid >= s) ? sd[tid - s] : 0;
            __syncthreads();
            sd[tid] += add;
            __syncthreads();
        }
        int total = sd[1023];
        int run = carry + ((tid > 0) ? sd[tid - 1] : 0);
#pragma unroll
        for (int j = 0; j < 4; ++j) {
            int idx = i0 + j;
            if (idx < n) {
                off[idx] = run;
                cnt_pos[idx] = run;
                run += v[j];
            }
        }
        carry += total;
    }
    if (tid == 0) off[n] = carry;
}

__global__ void fill_csr(const int* __restrict__ src, const int* __restrict__ tgt,
                         int* __restrict__ pos, int* __restrict__ esrc, int e) {
    for (int i = blockIdx.x * blockDim.x + threadIdx.x; i < e; i += gridDim.x * blockDim.x) {
        int p = atomicAdd(&pos[tgt[i]], 1);
        esrc[p] = src[i];
    }
}

// ---------------- gather-aggregate (one wave per node) ----------------

__global__ __launch_bounds__(256) void gather_agg(const float* __restrict__ xin,
                                                  const int* __restrict__ off,
                                                  const int* __restrict__ esrc,
                                                  float* __restrict__ agg, int n) {
    int lane = threadIdx.x & 63;
    int node = blockIdx.x * 4 + (threadIdx.x >> 6);
    if (node >= n) return;
    int beg = off[node], end = off[node + 1];
    float ax = 0.f, ay = 0.f;
    for (int j = beg; j < end; ++j) {
        int s = esrc[j];
        const float2 v = *(const float2*)(xin + (size_t)s * DD + lane * 2);
        ax += v.x;
        ay += v.y;
    }
    float2 r;
    r.x = ax;
    r.y = ay;
    *(float2*)(agg + (size_t)node * DD + lane * 2) = r;
}

// ---------------- fused dual-GEMM + bias + relu ----------------
// out = relu(Aagg @ Wrel^T + Aroot @ Wroot^T + bias)
// Aagg/Aroot: [n][128] row-major, W*: [128][128] row-major, bias: [128]
// In-place safe when out == Aroot: each block reads only its own 64 rows
// (clamped index stays inside the block's row range) and writes after all reads.
__global__ __launch_bounds__(256) void gemm_fused(const float* __restrict__ Aagg,
                                                  const float* __restrict__ Aroot,
                                                  const float* __restrict__ Wrel,
                                                  const float* __restrict__ Wroot,
                                                  const float* __restrict__ bias,
                                                  float* __restrict__ out, int n) {
    __shared__ float sAa[64][16];
    __shared__ float sAr[64][16];
    __shared__ float sWr[128][17];   // +1 pad: read stride 17 -> conflict-free
    __shared__ float sWo[128][17];

    int t = threadIdx.x;
    int r0 = blockIdx.x * 64;
    int tc = t & 31;       // cols tc, tc+32, tc+64, tc+96
    int tr = t >> 5;       // rows tr*8 .. tr*8+7

    float acc[8][4];
#pragma unroll
    for (int i = 0; i < 8; ++i)
#pragma unroll
        for (int j = 0; j < 4; ++j) acc[i][j] = 0.f;

    int arow = t >> 2;
    int ak = (t & 3) * 4;
    int gr = r0 + arow;
    if (gr > n - 1) gr = n - 1;      // clamp stays within this block's rows
    const float* pAa = Aagg + (size_t)gr * DD + ak;
    const float* pAr = Aroot + (size_t)gr * DD + ak;

    for (int k0 = 0; k0 < DD; k0 += 16) {
        float4 va = *(const float4*)(pAa + k0);
        float4 vr = *(const float4*)(pAr + k0);
        *(float4*)&sAa[arow][ak] = va;   // [64][16]: 16B-aligned
        *(float4*)&sAr[arow][ak] = vr;
#pragma unroll
        for (int u = 0; u < 2; ++u) {
            int idx = t + u * 256;
            int wr = idx >> 2;
            int wk = (idx & 3) * 4;
            float4 w1 = *(const float4*)(Wrel + (size_t)wr * DD + k0 + wk);
            float4 w2 = *(const float4*)(Wroot + (size_t)wr * DD + k0 + wk);
            sWr[wr][wk + 0] = w1.x; sWr[wr][wk + 1] = w1.y;
            sWr[wr][wk + 2] = w1.z; sWr[wr][wk + 3] = w1.w;
            sWo[wr][wk + 0] = w2.x; sWo[wr][wk + 1] = w2.y;
            sWo[wr][wk + 2] = w2.z; sWo[wr][wk + 3] = w2.w;
        }
        __syncthreads();
#pragma unroll
        for (int k = 0; k < 16; ++k) {
            float aa[8], ar[8], wl[4], wo[4];
#pragma unroll
            for (int j = 0; j < 4; ++j) {
                wl[j] = sWr[tc + 32 * j][k];
                wo[j] = sWo[tc + 32 * j][k];
            }
#pragma unroll
            for (int i = 0; i < 8; ++i) {
                aa[i] = sAa[tr * 8 + i][k];
                ar[i] = sAr[tr * 8 + i][k];
            }
#pragma unroll
            for (int i = 0; i < 8; ++i)
#pragma unroll
                for (int j = 0; j < 4; ++j)
                    acc[i][j] += aa[i] * wl[j] + ar[i] * wo[j];
        }
        __syncthreads();
    }

#pragma unroll
    for (int i = 0; i < 8; ++i) {
        int row = r0 + tr * 8 + i;
        if (row < n) {
#pragma unroll
            for (int j = 0; j < 4; ++j) {
                int col = tc + 32 * j;
                float v = acc[i][j] + bias[col];
                out[(size_t)row * DD + col] = v > 0.f ? v : 0.f;
            }
        }
    }
}

extern "C" void kernel_launch(void* const* d_in, const int* in_sizes, int n_in,
                              void* d_out, int out_size, void* d_ws, size_t ws_size,
                              hipStream_t stream) {
    const float* x = (const float*)d_in[0];
    const int* ei = (const int*)d_in[1];
    const float* W1rel = (const float*)d_in[2];
    const float* b1 = (const float*)d_in[3];
    const float* W1root = (const float*)d_in[4];
    const float* W2rel = (const float*)d_in[5];
    const float* b2 = (const float*)d_in[6];
    const float* W2root = (const float*)d_in[7];
    float* out = (float*)d_out;

    const int n = in_sizes[0] / DD;        // 50000
    const int e = in_sizes[1] / 2;         // 600000
    const int* src = ei;
    const int* tgt = ei + e;

    // workspace layout (all regions fully rewritten every call)
    char* ws = (char*)d_ws;
    int* off  = (int*)ws;                      // (n+1) ints
    int* pos  = (int*)(ws + 200064);           // n ints (counts -> cursors)
    int* esrc = (int*)(ws + 400128);           // e ints
    float* agg = (float*)(ws + 2800128);       // n*128 floats

    hipMemsetAsync(pos, 0, (size_t)n * sizeof(int), stream);
    count_edges<<<1024, 256, 0, stream>>>(tgt, pos, e);
    scan_excl<<<1, 1024, 0, stream>>>(pos, off, n);
    fill_csr<<<1024, 256, 0, stream>>>(src, tgt, pos, esrc, e);

    // layer 1: h (stored in d_out)
    gather_agg<<<(n + 3) / 4, 256, 0, stream>>>(x, off, esrc, agg, n);
    gemm_fused<<<(n + 63) / 64, 256, 0, stream>>>(agg, x, W1rel, W1root, b1, out, n);

    // layer 2: in-place on d_out
    gather_agg<<<(n + 3) / 4, 256, 0, stream>>>(out, off, esrc, agg, n);
    gemm_fused<<<(n + 63) / 64, 256, 0, stream>>>(agg, out, W2rel, W2root, b2, out, n);
}

// Round 2
// 353.260 us; speedup vs baseline: 1.4880x; 1.4880x over previous
//
#include <hip/hip_runtime.h>
#include <hip/hip_bf16.h>

#define DD 128

typedef __attribute__((ext_vector_type(8))) short bf16x8;
typedef __attribute__((ext_vector_type(4))) float f32x4;
typedef unsigned short ushort_t;
typedef unsigned int uint_t;

__device__ inline ushort_t f2bf(float f) {
    __hip_bfloat16 h = __float2bfloat16(f);
    union { __hip_bfloat16 h; ushort_t u; } cv;
    cv.h = h;
    return cv.u;
}
__device__ inline float bf2f(uint_t lo16) {
    union { uint_t i; float f; } v;
    v.i = lo16 << 16;
    return v.f;
}

// ---------------- CSR build ----------------

__global__ void count_edges(const int* __restrict__ tgt, int* __restrict__ cnt, int e) {
    for (int i = blockIdx.x * blockDim.x + threadIdx.x; i < e; i += gridDim.x * blockDim.x)
        atomicAdd(&cnt[tgt[i]], 1);
}

// single-block scan, each thread owns a contiguous chunk; 1 barrier total
__global__ __launch_bounds__(1024) void scan_excl(int* __restrict__ cnt_pos, int* __restrict__ off, int n) {
    const int CH = (n + 1023) / 1024;
    const int t = threadIdx.x;
    const int base = t * CH;
    int s = 0;
    for (int j = 0; j < CH; ++j) {
        int idx = base + j;
        if (idx < n) s += cnt_pos[idx];
    }
    const int lane = t & 63, wv = t >> 6;
    int v = s;
    for (int d = 1; d < 64; d <<= 1) {
        int o = __shfl_up(v, d, 64);
        if (lane >= d) v += o;
    }
    __shared__ int wsum[16];
    if (lane == 63) wsum[wv] = v;
    __syncthreads();
    int woff = 0;
    for (int i = 0; i < wv; ++i) woff += wsum[i];
    int run = woff + v - s;   // exclusive prefix for this chunk
    for (int j = 0; j < CH; ++j) {
        int idx = base + j;
        if (idx < n) {
            int c = cnt_pos[idx];
            off[idx] = run;
            cnt_pos[idx] = run;
            run += c;
        }
    }
    if (t == 1023) off[n] = run;
}

__global__ void fill_csr(const int* __restrict__ src, const int* __restrict__ tgt,
                         int* __restrict__ pos, int* __restrict__ esrc, int e) {
    for (int i = blockIdx.x * blockDim.x + threadIdx.x; i < e; i += gridDim.x * blockDim.x) {
        int p = atomicAdd(&pos[tgt[i]], 1);
        esrc[p] = src[i];
    }
}

// ---------------- conversions ----------------

__global__ void convert_f32_bf16(const float* __restrict__ in, ushort_t* __restrict__ outp, int n8) {
    int i = blockIdx.x * blockDim.x + threadIdx.x;
    if (i >= n8) return;
    const float4 a = *(const float4*)(in + (size_t)i * 8);
    const float4 b = *(const float4*)(in + (size_t)i * 8 + 4);
    ushort_t r[8];
    r[0] = f2bf(a.x); r[1] = f2bf(a.y); r[2] = f2bf(a.z); r[3] = f2bf(a.w);
    r[4] = f2bf(b.x); r[5] = f2bf(b.y); r[6] = f2bf(b.z); r[7] = f2bf(b.w);
    *(bf16x8*)(outp + (size_t)i * 8) = *(bf16x8*)r;
}

__global__ void convert_w4(const float* __restrict__ a, const float* __restrict__ b,
                           const float* __restrict__ c, const float* __restrict__ d,
                           ushort_t* __restrict__ o) {
    int i = blockIdx.x * blockDim.x + threadIdx.x;   // 65536 total
    if (i >= 65536) return;
    const float* p = (i < 16384) ? a : (i < 32768) ? b : (i < 49152) ? c : d;
    o[i] = f2bf(p[i & 16383]);
}

// ---------------- gather-aggregate (one wave per node, bf16 rows) ----------------

__global__ __launch_bounds__(256) void gather_agg_bf16(const ushort_t* __restrict__ xin,
                                                       const int* __restrict__ off,
                                                       const int* __restrict__ esrc,
                                                       ushort_t* __restrict__ agg, int n) {
    const int lane = threadIdx.x & 63;
    const int node = blockIdx.x * 4 + (threadIdx.x >> 6);
    if (node >= n) return;
    const int beg = off[node], end = off[node + 1];
    float ax = 0.f, ay = 0.f;
    int j = beg;
    for (; j + 1 < end; j += 2) {
        int s0 = esrc[j], s1 = esrc[j + 1];
        uint_t v0 = *(const uint_t*)(xin + (size_t)s0 * DD + lane * 2);
        uint_t v1 = *(const uint_t*)(xin + (size_t)s1 * DD + lane * 2);
        ax += bf2f(v0 & 0xffffu) + bf2f(v1 & 0xffffu);
        ay += bf2f(v0 >> 16) + bf2f(v1 >> 16);
    }
    if (j < end) {
        uint_t v0 = *(const uint_t*)(xin + (size_t)esrc[j] * DD + lane * 2);
        ax += bf2f(v0 & 0xffffu);
        ay += bf2f(v0 >> 16);
    }
    uint_t r = ((uint_t)f2bf(ay) << 16) | (uint_t)f2bf(ax);
    *(uint_t*)(agg + (size_t)node * DD + lane * 2) = r;
}

// ---------------- MFMA dual-GEMM + bias + relu ----------------
// out = relu(Aagg @ Wrel^T + Aroot @ Wroot^T + bias)
// A fragment: lane holds A[rbase + (lane&15)][8*(lane>>4) + k0 .. +7]  (16B contiguous)
// B fragment: lane holds W[j*16 + (lane&15)][8*(lane>>4) + k0 .. +7]   (W is [n][k] row-major = B^T)
// D: row = (lane>>4)*4 + i, col = j*16 + (lane&15)
// In-place safe when outv == Aagg: rows are wave-disjoint; all loads' data are
// consumed (waitcnt) before any store issues.
template<bool OUT_BF16>
__global__ __launch_bounds__(256) void gemm_mfma(
    const ushort_t* Aagg, const ushort_t* __restrict__ Aroot,
    const ushort_t* __restrict__ Wrel, const ushort_t* __restrict__ Wroot,
    const float* __restrict__ bias, void* outv, int n)
{
    const int wave = threadIdx.x >> 6;
    const int lane = threadIdx.x & 63;
    const int m = lane & 15;
    const int kg = lane >> 4;
    const int rbase = blockIdx.x * 64 + wave * 16;
    if (rbase >= n) return;               // n % 16 == 0: active waves fully valid
    const size_t aoff = (size_t)(rbase + m) * DD + kg * 8;

    f32x4 acc[8];
#pragma unroll
    for (int j = 0; j < 8; ++j) acc[j] = (f32x4){0.f, 0.f, 0.f, 0.f};

#pragma unroll
    for (int k0 = 0; k0 < DD; k0 += 32) {
        bf16x8 aA = *(const bf16x8*)(Aagg + aoff + k0);
        bf16x8 aR = *(const bf16x8*)(Aroot + aoff + k0);
#pragma unroll
        for (int j = 0; j < 8; ++j) {
            bf16x8 bL = *(const bf16x8*)(Wrel + (size_t)(j * 16 + m) * DD + kg * 8 + k0);
            bf16x8 bR = *(const bf16x8*)(Wroot + (size_t)(j * 16 + m) * DD + kg * 8 + k0);
            acc[j] = __builtin_amdgcn_mfma_f32_16x16x32_bf16(aA, bL, acc[j], 0, 0, 0);
            acc[j] = __builtin_amdgcn_mfma_f32_16x16x32_bf16(aR, bR, acc[j], 0, 0, 0);
        }
    }

    const int orow = rbase + kg * 4;
#pragma unroll
    for (int j = 0; j < 8; ++j) {
        const int col = j * 16 + m;
        const float bv = bias[col];
#pragma unroll
        for (int i = 0; i < 4; ++i) {
            float v = acc[j][i] + bv;
            v = v > 0.f ? v : 0.f;
            if (OUT_BF16)
                ((ushort_t*)outv)[(size_t)(orow + i) * DD + col] = f2bf(v);
            else
                ((float*)outv)[(size_t)(orow + i) * DD + col] = v;
        }
    }
}

extern "C" void kernel_launch(void* const* d_in, const int* in_sizes, int n_in,
                              void* d_out, int out_size, void* d_ws, size_t ws_size,
                              hipStream_t stream) {
    const float* x = (const float*)d_in[0];
    const int* ei = (const int*)d_in[1];
    const float* W1rel = (const float*)d_in[2];
    const float* b1 = (const float*)d_in[3];
    const float* W1root = (const float*)d_in[4];
    const float* W2rel = (const float*)d_in[5];
    const float* b2 = (const float*)d_in[6];
    const float* W2root = (const float*)d_in[7];
    float* out = (float*)d_out;

    const int n = in_sizes[0] / DD;        // 50000
    const int e = in_sizes[1] / 2;         // 600000
    const int* src = ei;
    const int* tgt = ei + e;

    // workspace layout (28.4 MB total, same footprint as the proven round-1 run)
    char* ws = (char*)d_ws;
    int* off = (int*)ws;                        // (n+1) ints          [0, 200004)
    int* pos = (int*)(ws + 200064);             // n ints, dead after fill_csr
    ushort_t* wb = (ushort_t*)(ws + 200064);    // 4x16384 bf16 weights, reuses pos
    int* esrc = (int*)(ws + 400128);            // e ints
    ushort_t* aggb = (ushort_t*)(ws + 2800128); // n*128 bf16: agg1, then h (in-place)
    ushort_t* xb = (ushort_t*)(ws + 15600128);  // n*128 bf16: x, then agg2

    hipMemsetAsync(pos, 0, (size_t)n * sizeof(int), stream);
    count_edges<<<1024, 256, 0, stream>>>(tgt, pos, e);
    scan_excl<<<1, 1024, 0, stream>>>(pos, off, n);
    fill_csr<<<1024, 256, 0, stream>>>(src, tgt, pos, esrc, e);
    convert_w4<<<256, 256, 0, stream>>>(W1rel, W1root, W2rel, W2root, wb);  // after fill: pos dead
    convert_f32_bf16<<<(n * DD / 8 + 255) / 256, 256, 0, stream>>>(x, xb, n * DD / 8);

    // layer 1: gather x -> aggb; gemm writes bf16 h in-place into aggb
    gather_agg_bf16<<<(n + 3) / 4, 256, 0, stream>>>(xb, off, esrc, aggb, n);
    gemm_mfma<true><<<(n + 63) / 64, 256, 0, stream>>>(aggb, xb, wb, wb + 16384, b1, aggb, n);

    // layer 2: gather h -> xb (agg2); gemm writes fp32 to d_out
    gather_agg_bf16<<<(n + 3) / 4, 256, 0, stream>>>(aggb, off, esrc, xb, n);
    gemm_mfma<false><<<(n + 63) / 64, 256, 0, stream>>>(xb, aggb, wb + 32768, wb + 49152, b2, out, n);
}

// Round 3
// 240.086 us; speedup vs baseline: 2.1894x; 1.4714x over previous
//
#include <hip/hip_runtime.h>
#include <hip/hip_bf16.h>

#define DD 128

typedef __attribute__((ext_vector_type(8))) short bf16x8;
typedef __attribute__((ext_vector_type(4))) float f32x4;
typedef unsigned short ushort_t;
typedef unsigned int uint_t;

__device__ inline ushort_t f2bf(float f) {
    __hip_bfloat16 h = __float2bfloat16(f);
    union { __hip_bfloat16 h; ushort_t u; } cv;
    cv.h = h;
    return cv.u;
}
__device__ inline float bf2f(uint_t lo16) {
    union { uint_t i; float f; } v;
    v.i = lo16 << 16;
    return v.f;
}

// ---------------- CSR build ----------------

__global__ void count_edges(const int* __restrict__ tgt, int* __restrict__ cnt, int e) {
    for (int i = blockIdx.x * blockDim.x + threadIdx.x; i < e; i += gridDim.x * blockDim.x)
        atomicAdd(&cnt[tgt[i]], 1);
}

// phase 1: per-block exclusive scan; off[i] = local excl prefix, bsum[b] = block total
__global__ __launch_bounds__(1024) void scan_part(const int* __restrict__ cnt,
                                                  int* __restrict__ off,
                                                  int* __restrict__ bsum, int n) {
    const int t = threadIdx.x;
    const int i = blockIdx.x * 1024 + t;
    const int v = (i < n) ? cnt[i] : 0;
    const int lane = t & 63, wv = t >> 6;
    int s = v;
#pragma unroll
    for (int d = 1; d < 64; d <<= 1) {
        int o = __shfl_up(s, d, 64);
        if (lane >= d) s += o;
    }
    __shared__ int wsum[16];
    if (lane == 63) wsum[wv] = s;
    __syncthreads();
    int woff = 0;
    for (int k = 0; k < wv; ++k) woff += wsum[k];
    if (i < n) off[i] = woff + s - v;          // local exclusive prefix
    if (t == 1023) bsum[blockIdx.x] = woff + s; // block total
}

// phase 2: one wave scans block totals in place (exclusive); off[n] = grand total
__global__ __launch_bounds__(64) void scan_bsum(int* __restrict__ bsum, int* __restrict__ off,
                                                int nb, int n) {
    const int t = threadIdx.x;
    const int v = (t < nb) ? bsum[t] : 0;
    int s = v;
#pragma unroll
    for (int d = 1; d < 64; d <<= 1) {
        int o = __shfl_up(s, d, 64);
        if (t >= d) s += o;
    }
    if (t < nb) bsum[t] = s - v;   // exclusive
    if (t == 63) off[n] = s;       // grand total (= e)
}

// phase 3: add block offsets; mirror into pos (fill cursors)
__global__ __launch_bounds__(1024) void scan_final(int* __restrict__ off,
                                                   const int* __restrict__ bsum,
                                                   int* __restrict__ pos, int n) {
    const int i = blockIdx.x * 1024 + threadIdx.x;
    if (i < n) {
        int r = off[i] + bsum[blockIdx.x];
        off[i] = r;
        pos[i] = r;
    }
}

__global__ void fill_csr(const int* __restrict__ src, const int* __restrict__ tgt,
                         int* __restrict__ pos, int* __restrict__ esrc, int e) {
    for (int i = blockIdx.x * blockDim.x + threadIdx.x; i < e; i += gridDim.x * blockDim.x) {
        int p = atomicAdd(&pos[tgt[i]], 1);
        esrc[p] = src[i];
    }
}

// ---------------- conversions ----------------

__global__ void convert_f32_bf16(const float* __restrict__ in, ushort_t* __restrict__ outp, int n8) {
    int i = blockIdx.x * blockDim.x + threadIdx.x;
    if (i >= n8) return;
    const float4 a = *(const float4*)(in + (size_t)i * 8);
    const float4 b = *(const float4*)(in + (size_t)i * 8 + 4);
    ushort_t r[8];
    r[0] = f2bf(a.x); r[1] = f2bf(a.y); r[2] = f2bf(a.z); r[3] = f2bf(a.w);
    r[4] = f2bf(b.x); r[5] = f2bf(b.y); r[6] = f2bf(b.z); r[7] = f2bf(b.w);
    *(bf16x8*)(outp + (size_t)i * 8) = *(bf16x8*)r;
}

__global__ void convert_w4(const float* __restrict__ a, const float* __restrict__ b,
                           const float* __restrict__ c, const float* __restrict__ d,
                           ushort_t* __restrict__ o) {
    int i = blockIdx.x * blockDim.x + threadIdx.x;   // 65536 total
    if (i >= 65536) return;
    const float* p = (i < 16384) ? a : (i < 32768) ? b : (i < 49152) ? c : d;
    o[i] = f2bf(p[i & 16383]);
}

// ---------------- gather-aggregate (one wave per node, bf16 rows) ----------------

__global__ __launch_bounds__(256) void gather_agg_bf16(const ushort_t* __restrict__ xin,
                                                       const int* __restrict__ off,
                                                       const int* __restrict__ esrc,
                                                       ushort_t* __restrict__ agg, int n) {
    const int lane = threadIdx.x & 63;
    const int node = blockIdx.x * 4 + (threadIdx.x >> 6);
    if (node >= n) return;
    const int beg = off[node], end = off[node + 1];
    float ax = 0.f, ay = 0.f;
    int j = beg;
    for (; j + 1 < end; j += 2) {
        int s0 = esrc[j], s1 = esrc[j + 1];
        uint_t v0 = *(const uint_t*)(xin + (size_t)s0 * DD + lane * 2);
        uint_t v1 = *(const uint_t*)(xin + (size_t)s1 * DD + lane * 2);
        ax += bf2f(v0 & 0xffffu) + bf2f(v1 & 0xffffu);
        ay += bf2f(v0 >> 16) + bf2f(v1 >> 16);
    }
    if (j < end) {
        uint_t v0 = *(const uint_t*)(xin + (size_t)esrc[j] * DD + lane * 2);
        ax += bf2f(v0 & 0xffffu);
        ay += bf2f(v0 >> 16);
    }
    uint_t r = ((uint_t)f2bf(ay) << 16) | (uint_t)f2bf(ax);
    *(uint_t*)(agg + (size_t)node * DD + lane * 2) = r;
}

// ---------------- MFMA dual-GEMM + bias + relu ----------------
// out = relu(Aagg @ Wrel^T + Aroot @ Wroot^T + bias)
// A fragment: lane holds A[rbase + (lane&15)][8*(lane>>4) + k0 .. +7]  (16B contiguous)
// B fragment: lane holds W[j*16 + (lane&15)][8*(lane>>4) + k0 .. +7]   (W is [n][k] row-major = B^T)
// D: row = (lane>>4)*4 + i, col = j*16 + (lane&15)
// In-place safe when outv == Aagg: rows are wave-disjoint; all loads' data are
// consumed (waitcnt) before any store issues.
template<bool OUT_BF16>
__global__ __launch_bounds__(256) void gemm_mfma(
    const ushort_t* Aagg, const ushort_t* __restrict__ Aroot,
    const ushort_t* __restrict__ Wrel, const ushort_t* __restrict__ Wroot,
    const float* __restrict__ bias, void* outv, int n)
{
    const int wave = threadIdx.x >> 6;
    const int lane = threadIdx.x & 63;
    const int m = lane & 15;
    const int kg = lane >> 4;
    const int rbase = blockIdx.x * 64 + wave * 16;
    if (rbase >= n) return;               // n % 16 == 0: active waves fully valid
    const size_t aoff = (size_t)(rbase + m) * DD + kg * 8;

    f32x4 acc[8];
#pragma unroll
    for (int j = 0; j < 8; ++j) acc[j] = (f32x4){0.f, 0.f, 0.f, 0.f};

#pragma unroll
    for (int k0 = 0; k0 < DD; k0 += 32) {
        bf16x8 aA = *(const bf16x8*)(Aagg + aoff + k0);
        bf16x8 aR = *(const bf16x8*)(Aroot + aoff + k0);
#pragma unroll
        for (int j = 0; j < 8; ++j) {
            bf16x8 bL = *(const bf16x8*)(Wrel + (size_t)(j * 16 + m) * DD + kg * 8 + k0);
            bf16x8 bR = *(const bf16x8*)(Wroot + (size_t)(j * 16 + m) * DD + kg * 8 + k0);
            acc[j] = __builtin_amdgcn_mfma_f32_16x16x32_bf16(aA, bL, acc[j], 0, 0, 0);
            acc[j] = __builtin_amdgcn_mfma_f32_16x16x32_bf16(aR, bR, acc[j], 0, 0, 0);
        }
    }

    const int orow = rbase + kg * 4;
#pragma unroll
    for (int j = 0; j < 8; ++j) {
        const int col = j * 16 + m;
        const float bv = bias[col];
#pragma unroll
        for (int i = 0; i < 4; ++i) {
            float v = acc[j][i] + bv;
            v = v > 0.f ? v : 0.f;
            if (OUT_BF16)
                ((ushort_t*)outv)[(size_t)(orow + i) * DD + col] = f2bf(v);
            else
                ((float*)outv)[(size_t)(orow + i) * DD + col] = v;
        }
    }
}

extern "C" void kernel_launch(void* const* d_in, const int* in_sizes, int n_in,
                              void* d_out, int out_size, void* d_ws, size_t ws_size,
                              hipStream_t stream) {
    const float* x = (const float*)d_in[0];
    const int* ei = (const int*)d_in[1];
    const float* W1rel = (const float*)d_in[2];
    const float* b1 = (const float*)d_in[3];
    const float* W1root = (const float*)d_in[4];
    const float* W2rel = (const float*)d_in[5];
    const float* b2 = (const float*)d_in[6];
    const float* W2root = (const float*)d_in[7];
    float* out = (float*)d_out;

    const int n = in_sizes[0] / DD;        // 50000
    const int e = in_sizes[1] / 2;         // 600000
    const int* src = ei;
    const int* tgt = ei + e;
    const int nb = (n + 1023) / 1024;      // 49 scan blocks

    // workspace layout (~28.4 MB)
    char* ws = (char*)d_ws;
    int* off  = (int*)ws;                        // (n+1) ints        [0, 200004)
    int* bsum = (int*)(ws + 200064);             // 64 ints           [200064, 200320)
    int* pos  = (int*)(ws + 200320);             // n ints (counts -> cursors), dead after fill
    ushort_t* wb = (ushort_t*)(ws + 200320);     // 4x16384 bf16 weights, reuses pos
    int* esrc = (int*)(ws + 400384);             // e ints            [400384, 2800384)
    ushort_t* aggb = (ushort_t*)(ws + 2800640);  // n*128 bf16: agg1, then h (in-place)
    ushort_t* xb = (ushort_t*)(ws + 15600640);   // n*128 bf16: x, then agg2

    hipMemsetAsync(pos, 0, (size_t)n * sizeof(int), stream);
    count_edges<<<1024, 256, 0, stream>>>(tgt, pos, e);
    scan_part<<<nb, 1024, 0, stream>>>(pos, off, bsum, n);
    scan_bsum<<<1, 64, 0, stream>>>(bsum, off, nb, n);
    scan_final<<<nb, 1024, 0, stream>>>(off, bsum, pos, n);
    fill_csr<<<1024, 256, 0, stream>>>(src, tgt, pos, esrc, e);
    convert_w4<<<256, 256, 0, stream>>>(W1rel, W1root, W2rel, W2root, wb);  // after fill: pos dead
    convert_f32_bf16<<<(n * DD / 8 + 255) / 256, 256, 0, stream>>>(x, xb, n * DD / 8);

    // layer 1: gather x -> aggb; gemm writes bf16 h in-place into aggb
    gather_agg_bf16<<<(n + 3) / 4, 256, 0, stream>>>(xb, off, esrc, aggb, n);
    gemm_mfma<true><<<(n + 63) / 64, 256, 0, stream>>>(aggb, xb, wb, wb + 16384, b1, aggb, n);

    // layer 2: gather h -> xb (agg2); gemm writes fp32 to d_out
    gather_agg_bf16<<<(n + 3) / 4, 256, 0, stream>>>(aggb, off, esrc, xb, n);
    gemm_mfma<false><<<(n + 63) / 64, 256, 0, stream>>>(xb, aggb, wb + 32768, wb + 49152, b2, out, n);
}

// Round 4
// 232.524 us; speedup vs baseline: 2.2606x; 1.0325x over previous
//
#include <hip/hip_runtime.h>
#include <hip/hip_bf16.h>

#define DD 128

typedef __attribute__((ext_vector_type(8))) short bf16x8;
typedef __attribute__((ext_vector_type(4))) float f32x4;
typedef unsigned short ushort_t;
typedef unsigned int uint_t;

__device__ inline ushort_t f2bf(float f) {
    __hip_bfloat16 h = __float2bfloat16(f);
    union { __hip_bfloat16 h; ushort_t u; } cv;
    cv.h = h;
    return cv.u;
}
__device__ inline float bf2f(uint_t lo16) {
    union { uint_t i; float f; } v;
    v.i = lo16 << 16;
    return v.f;
}

// ---------------- CSR build ----------------

__global__ __launch_bounds__(256) void zero_pos(int* __restrict__ p, int n4) {
    int i = blockIdx.x * 256 + threadIdx.x;
    if (i < n4) ((int4*)p)[i] = make_int4(0, 0, 0, 0);
}

__global__ __launch_bounds__(256) void count_edges(const int* __restrict__ tgt,
                                                   int* __restrict__ cnt, int e) {
    int i = blockIdx.x * 256 + threadIdx.x;
    int e4 = e >> 2;
    if (i < e4) {
        int4 t = ((const int4*)tgt)[i];
        atomicAdd(&cnt[t.x], 1);
        atomicAdd(&cnt[t.y], 1);
        atomicAdd(&cnt[t.z], 1);
        atomicAdd(&cnt[t.w], 1);
    }
    if (i == 0)
        for (int j = e4 * 4; j < e; ++j) atomicAdd(&cnt[tgt[j]], 1);
}

// phase 1: per-block exclusive scan; off[i] = local excl prefix, bsum[b] = block total
__global__ __launch_bounds__(1024) void scan_part(const int* __restrict__ cnt,
                                                  int* __restrict__ off,
                                                  int* __restrict__ bsum, int n) {
    const int t = threadIdx.x;
    const int i = blockIdx.x * 1024 + t;
    const int v = (i < n) ? cnt[i] : 0;
    const int lane = t & 63, wv = t >> 6;
    int s = v;
#pragma unroll
    for (int d = 1; d < 64; d <<= 1) {
        int o = __shfl_up(s, d, 64);
        if (lane >= d) s += o;
    }
    __shared__ int wsum[16];
    if (lane == 63) wsum[wv] = s;
    __syncthreads();
    int woff = 0;
    for (int k = 0; k < wv; ++k) woff += wsum[k];
    if (i < n) off[i] = woff + s - v;           // local exclusive prefix
    if (t == 1023) bsum[blockIdx.x] = woff + s; // block total
}

// phase 2: one wave scans block totals in place (exclusive); off[n] = grand total
__global__ __launch_bounds__(64) void scan_bsum(int* __restrict__ bsum, int* __restrict__ off,
                                                int nb, int n) {
    const int t = threadIdx.x;
    const int v = (t < nb) ? bsum[t] : 0;
    int s = v;
#pragma unroll
    for (int d = 1; d < 64; d <<= 1) {
        int o = __shfl_up(s, d, 64);
        if (t >= d) s += o;
    }
    if (t < nb) bsum[t] = s - v;   // exclusive
    if (t == 63) off[n] = s;       // grand total (= e)
}

// phase 3: add block offsets; mirror into pos (fill cursors)
__global__ __launch_bounds__(1024) void scan_final(int* __restrict__ off,
                                                   const int* __restrict__ bsum,
                                                   int* __restrict__ pos, int n) {
    const int i = blockIdx.x * 1024 + threadIdx.x;
    if (i < n) {
        int r = off[i] + bsum[blockIdx.x];
        off[i] = r;
        pos[i] = r;
    }
}

__global__ __launch_bounds__(256) void fill_csr(const int* __restrict__ src,
                                                const int* __restrict__ tgt,
                                                int* __restrict__ pos,
                                                ushort_t* __restrict__ esrc, int e) {
    int i = blockIdx.x * 256 + threadIdx.x;
    int e4 = e >> 2;
    if (i < e4) {
        int4 t = ((const int4*)tgt)[i];
        int4 s = ((const int4*)src)[i];
        esrc[atomicAdd(&pos[t.x], 1)] = (ushort_t)s.x;
        esrc[atomicAdd(&pos[t.y], 1)] = (ushort_t)s.y;
        esrc[atomicAdd(&pos[t.z], 1)] = (ushort_t)s.z;
        esrc[atomicAdd(&pos[t.w], 1)] = (ushort_t)s.w;
    }
    if (i == 0)
        for (int j = e4 * 4; j < e; ++j)
            esrc[atomicAdd(&pos[tgt[j]], 1)] = (ushort_t)src[j];
}

// ---------------- conversions ----------------

__global__ void convert_f32_bf16(const float* __restrict__ in, ushort_t* __restrict__ outp, int n8) {
    int i = blockIdx.x * blockDim.x + threadIdx.x;
    if (i >= n8) return;
    const float4 a = *(const float4*)(in + (size_t)i * 8);
    const float4 b = *(const float4*)(in + (size_t)i * 8 + 4);
    ushort_t r[8];
    r[0] = f2bf(a.x); r[1] = f2bf(a.y); r[2] = f2bf(a.z); r[3] = f2bf(a.w);
    r[4] = f2bf(b.x); r[5] = f2bf(b.y); r[6] = f2bf(b.z); r[7] = f2bf(b.w);
    *(bf16x8*)(outp + (size_t)i * 8) = *(bf16x8*)r;
}

__global__ void convert_w4(const float* __restrict__ a, const float* __restrict__ b,
                           const float* __restrict__ c, const float* __restrict__ d,
                           ushort_t* __restrict__ o) {
    int i = blockIdx.x * blockDim.x + threadIdx.x;   // 65536 total
    if (i >= 65536) return;
    const float* p = (i < 16384) ? a : (i < 32768) ? b : (i < 49152) ? c : d;
    o[i] = f2bf(p[i & 16383]);
}

// ---------------- gather-aggregate (one wave per node, bf16 rows) ----------------

__global__ __launch_bounds__(256) void gather_agg_bf16(const ushort_t* __restrict__ xin,
                                                       const int* __restrict__ off,
                                                       const ushort_t* __restrict__ esrc,
                                                       ushort_t* __restrict__ agg, int n) {
    const int lane = threadIdx.x & 63;
    const int node = blockIdx.x * 4 + (threadIdx.x >> 6);
    if (node >= n) return;
    const int beg = off[node], end = off[node + 1];
    float ax = 0.f, ay = 0.f;
    int j = beg;
    for (; j + 1 < end; j += 2) {
        int s0 = esrc[j], s1 = esrc[j + 1];
        uint_t v0 = *(const uint_t*)(xin + (size_t)s0 * DD + lane * 2);
        uint_t v1 = *(const uint_t*)(xin + (size_t)s1 * DD + lane * 2);
        ax += bf2f(v0 & 0xffffu) + bf2f(v1 & 0xffffu);
        ay += bf2f(v0 >> 16) + bf2f(v1 >> 16);
    }
    if (j < end) {
        uint_t v0 = *(const uint_t*)(xin + (size_t)esrc[j] * DD + lane * 2);
        ax += bf2f(v0 & 0xffffu);
        ay += bf2f(v0 >> 16);
    }
    uint_t r = ((uint_t)f2bf(ay) << 16) | (uint_t)f2bf(ax);
    *(uint_t*)(agg + (size_t)node * DD + lane * 2) = r;
}

// ---------------- MFMA dual-GEMM + bias + relu ----------------
// out = relu(Aagg @ Wrel^T + Aroot @ Wroot^T + bias)
// A fragment: lane holds A[rbase + (lane&15)][8*(lane>>4) + k0 .. +7]  (16B contiguous)
// B fragment: lane holds W[j*16 + (lane&15)][8*(lane>>4) + k0 .. +7]   (W is [n][k] row-major = B^T)
// D: row = (lane>>4)*4 + i, col = j*16 + (lane&15)
// In-place safe when outv == Aagg: rows are wave-disjoint; all loads' data are
// consumed (waitcnt) before any store issues.
template<bool OUT_BF16>
__global__ __launch_bounds__(256) void gemm_mfma(
    const ushort_t* Aagg, const ushort_t* __restrict__ Aroot,
    const ushort_t* __restrict__ Wrel, const ushort_t* __restrict__ Wroot,
    const float* __restrict__ bias, void* outv, int n)
{
    const int wave = threadIdx.x >> 6;
    const int lane = threadIdx.x & 63;
    const int m = lane & 15;
    const int kg = lane >> 4;
    const int rbase = blockIdx.x * 64 + wave * 16;
    if (rbase >= n) return;               // n % 16 == 0: active waves fully valid
    const size_t aoff = (size_t)(rbase + m) * DD + kg * 8;

    f32x4 acc[8];
#pragma unroll
    for (int j = 0; j < 8; ++j) acc[j] = (f32x4){0.f, 0.f, 0.f, 0.f};

#pragma unroll
    for (int k0 = 0; k0 < DD; k0 += 32) {
        bf16x8 aA = *(const bf16x8*)(Aagg + aoff + k0);
        bf16x8 aR = *(const bf16x8*)(Aroot + aoff + k0);
#pragma unroll
        for (int j = 0; j < 8; ++j) {
            bf16x8 bL = *(const bf16x8*)(Wrel + (size_t)(j * 16 + m) * DD + kg * 8 + k0);
            bf16x8 bR = *(const bf16x8*)(Wroot + (size_t)(j * 16 + m) * DD + kg * 8 + k0);
            acc[j] = __builtin_amdgcn_mfma_f32_16x16x32_bf16(aA, bL, acc[j], 0, 0, 0);
            acc[j] = __builtin_amdgcn_mfma_f32_16x16x32_bf16(aR, bR, acc[j], 0, 0, 0);
        }
    }

    const int orow = rbase + kg * 4;
#pragma unroll
    for (int j = 0; j < 8; ++j) {
        const int col = j * 16 + m;
        const float bv = bias[col];
#pragma unroll
        for (int i = 0; i < 4; ++i) {
            float v = acc[j][i] + bv;
            v = v > 0.f ? v : 0.f;
            if (OUT_BF16)
                ((ushort_t*)outv)[(size_t)(orow + i) * DD + col] = f2bf(v);
            else
                ((float*)outv)[(size_t)(orow + i) * DD + col] = v;
        }
    }
}

extern "C" void kernel_launch(void* const* d_in, const int* in_sizes, int n_in,
                              void* d_out, int out_size, void* d_ws, size_t ws_size,
                              hipStream_t stream) {
    const float* x = (const float*)d_in[0];
    const int* ei = (const int*)d_in[1];
    const float* W1rel = (const float*)d_in[2];
    const float* b1 = (const float*)d_in[3];
    const float* W1root = (const float*)d_in[4];
    const float* W2rel = (const float*)d_in[5];
    const float* b2 = (const float*)d_in[6];
    const float* W2root = (const float*)d_in[7];
    float* out = (float*)d_out;

    const int n = in_sizes[0] / DD;        // 50000
    const int e = in_sizes[1] / 2;         // 600000
    const int* src = ei;
    const int* tgt = ei + e;
    const int nb = (n + 1023) / 1024;      // 49 scan blocks

    // workspace layout (~27 MB)
    char* ws = (char*)d_ws;
    int* off  = (int*)ws;                        // (n+1) ints        [0, 200004)
    int* bsum = (int*)(ws + 200064);             // 64 ints
    int* pos  = (int*)(ws + 200320);             // n ints (counts -> cursors), dead after fill
    ushort_t* wb = (ushort_t*)(ws + 200320);     // 4x16384 bf16 weights, reuses pos
    ushort_t* esrc = (ushort_t*)(ws + 400384);   // e ushorts (1.2MB)
    ushort_t* aggb = (ushort_t*)(ws + 2800640);  // n*128 bf16: agg1, then h (in-place)
    ushort_t* xb = (ushort_t*)(ws + 15600640);   // n*128 bf16: x, then agg2

    zero_pos<<<(n / 4 + 255) / 256, 256, 0, stream>>>(pos, n / 4);
    count_edges<<<(e / 4 + 255) / 256, 256, 0, stream>>>(tgt, pos, e);
    scan_part<<<nb, 1024, 0, stream>>>(pos, off, bsum, n);
    scan_bsum<<<1, 64, 0, stream>>>(bsum, off, nb, n);
    scan_final<<<nb, 1024, 0, stream>>>(off, bsum, pos, n);
    fill_csr<<<(e / 4 + 255) / 256, 256, 0, stream>>>(src, tgt, pos, esrc, e);
    convert_w4<<<256, 256, 0, stream>>>(W1rel, W1root, W2rel, W2root, wb);  // after fill: pos dead
    convert_f32_bf16<<<(n * DD / 8 + 255) / 256, 256, 0, stream>>>(x, xb, n * DD / 8);

    // layer 1: gather x -> aggb; gemm writes bf16 h in-place into aggb
    gather_agg_bf16<<<(n + 3) / 4, 256, 0, stream>>>(xb, off, esrc, aggb, n);
    gemm_mfma<true><<<(n + 63) / 64, 256, 0, stream>>>(aggb, xb, wb, wb + 16384, b1, aggb, n);

    // layer 2: gather h -> xb (agg2); gemm writes fp32 to d_out
    gather_agg_bf16<<<(n + 3) / 4, 256, 0, stream>>>(aggb, off, esrc, xb, n);
    gemm_mfma<false><<<(n + 63) / 64, 256, 0, stream>>>(xb, aggb, wb + 32768, wb + 49152, b2, out, n);
}

// Round 5
// 202.210 us; speedup vs baseline: 2.5995x; 1.1499x over previous
//
#include <hip/hip_runtime.h>
#include <hip/hip_bf16.h>

#define DD 128

typedef __attribute__((ext_vector_type(8))) short bf16x8;
typedef __attribute__((ext_vector_type(4))) float f32x4;
typedef unsigned short ushort_t;
typedef unsigned int uint_t;

__device__ inline ushort_t f2bf(float f) {
    __hip_bfloat16 h = __float2bfloat16(f);
    union { __hip_bfloat16 h; ushort_t u; } cv;
    cv.h = h;
    return cv.u;
}
__device__ inline float bf2f(uint_t lo16) {
    union { uint_t i; float f; } v;
    v.i = lo16 << 16;
    return v.f;
}

// ---------------- CSR build ----------------

__global__ __launch_bounds__(256) void zero_pos(int* __restrict__ p, int n4) {
    int i = blockIdx.x * 256 + threadIdx.x;
    if (i < n4) ((int4*)p)[i] = make_int4(0, 0, 0, 0);
}

__global__ __launch_bounds__(256) void count_edges(const int* __restrict__ tgt,
                                                   int* __restrict__ cnt, int e) {
    int i = blockIdx.x * 256 + threadIdx.x;
    int e4 = e >> 2;
    if (i < e4) {
        int4 t = ((const int4*)tgt)[i];
        atomicAdd(&cnt[t.x], 1);
        atomicAdd(&cnt[t.y], 1);
        atomicAdd(&cnt[t.z], 1);
        atomicAdd(&cnt[t.w], 1);
    }
    if (i == 0)
        for (int j = e4 * 4; j < e; ++j) atomicAdd(&cnt[tgt[j]], 1);
}

// phase 1: per-block exclusive scan; off[i] = local excl prefix, bsum[b] = block total
__global__ __launch_bounds__(1024) void scan_part(const int* __restrict__ cnt,
                                                  int* __restrict__ off,
                                                  int* __restrict__ bsum, int n) {
    const int t = threadIdx.x;
    const int i = blockIdx.x * 1024 + t;
    const int v = (i < n) ? cnt[i] : 0;
    const int lane = t & 63, wv = t >> 6;
    int s = v;
#pragma unroll
    for (int d = 1; d < 64; d <<= 1) {
        int o = __shfl_up(s, d, 64);
        if (lane >= d) s += o;
    }
    __shared__ int wsum[16];
    if (lane == 63) wsum[wv] = s;
    __syncthreads();
    int woff = 0;
    for (int k = 0; k < wv; ++k) woff += wsum[k];
    if (i < n) off[i] = woff + s - v;           // local exclusive prefix
    if (t == 1023) bsum[blockIdx.x] = woff + s; // block total
}

// phase 2: one wave scans block totals in place (exclusive); off[n] = grand total
__global__ __launch_bounds__(64) void scan_bsum(int* __restrict__ bsum, int* __restrict__ off,
                                                int nb, int n) {
    const int t = threadIdx.x;
    const int v = (t < nb) ? bsum[t] : 0;
    int s = v;
#pragma unroll
    for (int d = 1; d < 64; d <<= 1) {
        int o = __shfl_up(s, d, 64);
        if (t >= d) s += o;
    }
    if (t < nb) bsum[t] = s - v;   // exclusive
    if (t == 63) off[n] = s;       // grand total (= e)
}

// phase 3: add block offsets; mirror into pos (fill cursors)
__global__ __launch_bounds__(1024) void scan_final(int* __restrict__ off,
                                                   const int* __restrict__ bsum,
                                                   int* __restrict__ pos, int n) {
    const int i = blockIdx.x * 1024 + threadIdx.x;
    if (i < n) {
        int r = off[i] + bsum[blockIdx.x];
        off[i] = r;
        pos[i] = r;
    }
}

__global__ __launch_bounds__(256) void fill_csr(const int* __restrict__ src,
                                                const int* __restrict__ tgt,
                                                int* __restrict__ pos,
                                                ushort_t* __restrict__ esrc, int e) {
    int i = blockIdx.x * 256 + threadIdx.x;
    int e4 = e >> 2;
    if (i < e4) {
        int4 t = ((const int4*)tgt)[i];
        int4 s = ((const int4*)src)[i];
        esrc[atomicAdd(&pos[t.x], 1)] = (ushort_t)s.x;
        esrc[atomicAdd(&pos[t.y], 1)] = (ushort_t)s.y;
        esrc[atomicAdd(&pos[t.z], 1)] = (ushort_t)s.z;
        esrc[atomicAdd(&pos[t.w], 1)] = (ushort_t)s.w;
    }
    if (i == 0)
        for (int j = e4 * 4; j < e; ++j)
            esrc[atomicAdd(&pos[tgt[j]], 1)] = (ushort_t)src[j];
}

// ---------------- conversions ----------------

__global__ void convert_f32_bf16(const float* __restrict__ in, ushort_t* __restrict__ outp, int n8) {
    int i = blockIdx.x * blockDim.x + threadIdx.x;
    if (i >= n8) return;
    const float4 a = *(const float4*)(in + (size_t)i * 8);
    const float4 b = *(const float4*)(in + (size_t)i * 8 + 4);
    ushort_t r[8];
    r[0] = f2bf(a.x); r[1] = f2bf(a.y); r[2] = f2bf(a.z); r[3] = f2bf(a.w);
    r[4] = f2bf(b.x); r[5] = f2bf(b.y); r[6] = f2bf(b.z); r[7] = f2bf(b.w);
    *(bf16x8*)(outp + (size_t)i * 8) = *(bf16x8*)r;
}

__global__ void convert_w4(const float* __restrict__ a, const float* __restrict__ b,
                           const float* __restrict__ c, const float* __restrict__ d,
                           ushort_t* __restrict__ o) {
    int i = blockIdx.x * blockDim.x + threadIdx.x;   // 65536 total
    if (i >= 65536) return;
    const float* p = (i < 16384) ? a : (i < 32768) ? b : (i < 49152) ? c : d;
    o[i] = f2bf(p[i & 16383]);
}

// ---------------- gather-aggregate (one wave per node, bf16 rows) ----------------
// K-deep software batch: K independent id loads (same cache line), then K
// independent 256B row loads in flight, one waitcnt per batch -> MLP = K.

template<int K>
__device__ inline void gath(const ushort_t* __restrict__ xrow,
                            const ushort_t* __restrict__ esrc, int j,
                            float& ax, float& ay) {
    int s[K];
    uint_t v[K];
#pragma unroll
    for (int k = 0; k < K; ++k) s[k] = esrc[j + k];
#pragma unroll
    for (int k = 0; k < K; ++k) v[k] = *(const uint_t*)(xrow + (size_t)s[k] * DD);
#pragma unroll
    for (int k = 0; k < K; ++k) {
        ax += bf2f(v[k] & 0xffffu);
        ay += bf2f(v[k] >> 16);
    }
}

__global__ __launch_bounds__(256) void gather_agg_bf16(const ushort_t* __restrict__ xin,
                                                       const int* __restrict__ off,
                                                       const ushort_t* __restrict__ esrc,
                                                       ushort_t* __restrict__ agg, int n) {
    const int lane = threadIdx.x & 63;
    const int node = blockIdx.x * 4 + (threadIdx.x >> 6);
    if (node >= n) return;
    const int beg = off[node], end = off[node + 1];
    const ushort_t* xrow = xin + lane * 2;
    float ax = 0.f, ay = 0.f;
    int j = beg;
    for (; j + 8 <= end; j += 8) gath<8>(xrow, esrc, j, ax, ay);
    if (j + 4 <= end) { gath<4>(xrow, esrc, j, ax, ay); j += 4; }
    if (j + 2 <= end) { gath<2>(xrow, esrc, j, ax, ay); j += 2; }
    if (j < end)      { gath<1>(xrow, esrc, j, ax, ay); }
    uint_t r = ((uint_t)f2bf(ay) << 16) | (uint_t)f2bf(ax);
    *(uint_t*)(agg + (size_t)node * DD + lane * 2) = r;
}

// ---------------- MFMA dual-GEMM + bias + relu ----------------
// out = relu(Aagg @ Wrel^T + Aroot @ Wroot^T + bias)
// A fragment: lane holds A[rbase + (lane&15)][8*(lane>>4) + k0 .. +7]  (16B contiguous)
// B fragment: lane holds W[j*16 + (lane&15)][8*(lane>>4) + k0 .. +7]   (W is [n][k] row-major = B^T)
// D: row = (lane>>4)*4 + i, col = j*16 + (lane&15)
// In-place safe when outv == Aagg: rows are wave-disjoint; all loads' data are
// consumed (waitcnt) before any store issues.
template<bool OUT_BF16>
__global__ __launch_bounds__(256) void gemm_mfma(
    const ushort_t* Aagg, const ushort_t* __restrict__ Aroot,
    const ushort_t* __restrict__ Wrel, const ushort_t* __restrict__ Wroot,
    const float* __restrict__ bias, void* outv, int n)
{
    const int wave = threadIdx.x >> 6;
    const int lane = threadIdx.x & 63;
    const int m = lane & 15;
    const int kg = lane >> 4;
    const int rbase = blockIdx.x * 64 + wave * 16;
    if (rbase >= n) return;               // n % 16 == 0: active waves fully valid
    const size_t aoff = (size_t)(rbase + m) * DD + kg * 8;

    f32x4 acc[8];
#pragma unroll
    for (int j = 0; j < 8; ++j) acc[j] = (f32x4){0.f, 0.f, 0.f, 0.f};

#pragma unroll
    for (int k0 = 0; k0 < DD; k0 += 32) {
        bf16x8 aA = *(const bf16x8*)(Aagg + aoff + k0);
        bf16x8 aR = *(const bf16x8*)(Aroot + aoff + k0);
#pragma unroll
        for (int j = 0; j < 8; ++j) {
            bf16x8 bL = *(const bf16x8*)(Wrel + (size_t)(j * 16 + m) * DD + kg * 8 + k0);
            bf16x8 bR = *(const bf16x8*)(Wroot + (size_t)(j * 16 + m) * DD + kg * 8 + k0);
            acc[j] = __builtin_amdgcn_mfma_f32_16x16x32_bf16(aA, bL, acc[j], 0, 0, 0);
            acc[j] = __builtin_amdgcn_mfma_f32_16x16x32_bf16(aR, bR, acc[j], 0, 0, 0);
        }
    }

    const int orow = rbase + kg * 4;
#pragma unroll
    for (int j = 0; j < 8; ++j) {
        const int col = j * 16 + m;
        const float bv = bias[col];
#pragma unroll
        for (int i = 0; i < 4; ++i) {
            float v = acc[j][i] + bv;
            v = v > 0.f ? v : 0.f;
            if (OUT_BF16)
                ((ushort_t*)outv)[(size_t)(orow + i) * DD + col] = f2bf(v);
            else
                ((float*)outv)[(size_t)(orow + i) * DD + col] = v;
        }
    }
}

extern "C" void kernel_launch(void* const* d_in, const int* in_sizes, int n_in,
                              void* d_out, int out_size, void* d_ws, size_t ws_size,
                              hipStream_t stream) {
    const float* x = (const float*)d_in[0];
    const int* ei = (const int*)d_in[1];
    const float* W1rel = (const float*)d_in[2];
    const float* b1 = (const float*)d_in[3];
    const float* W1root = (const float*)d_in[4];
    const float* W2rel = (const float*)d_in[5];
    const float* b2 = (const float*)d_in[6];
    const float* W2root = (const float*)d_in[7];
    float* out = (float*)d_out;

    const int n = in_sizes[0] / DD;        // 50000
    const int e = in_sizes[1] / 2;         // 600000
    const int* src = ei;
    const int* tgt = ei + e;
    const int nb = (n + 1023) / 1024;      // 49 scan blocks

    // workspace layout (~27 MB)
    char* ws = (char*)d_ws;
    int* off  = (int*)ws;                        // (n+1) ints        [0, 200004)
    int* bsum = (int*)(ws + 200064);             // 64 ints
    int* pos  = (int*)(ws + 200320);             // n ints (counts -> cursors), dead after fill
    ushort_t* wb = (ushort_t*)(ws + 200320);     // 4x16384 bf16 weights, reuses pos
    ushort_t* esrc = (ushort_t*)(ws + 400384);   // e ushorts (1.2MB)
    ushort_t* aggb = (ushort_t*)(ws + 2800640);  // n*128 bf16: agg1, then h (in-place)
    ushort_t* xb = (ushort_t*)(ws + 15600640);   // n*128 bf16: x, then agg2

    zero_pos<<<(n / 4 + 255) / 256, 256, 0, stream>>>(pos, n / 4);
    count_edges<<<(e / 4 + 255) / 256, 256, 0, stream>>>(tgt, pos, e);
    scan_part<<<nb, 1024, 0, stream>>>(pos, off, bsum, n);
    scan_bsum<<<1, 64, 0, stream>>>(bsum, off, nb, n);
    scan_final<<<nb, 1024, 0, stream>>>(off, bsum, pos, n);
    fill_csr<<<(e / 4 + 255) / 256, 256, 0, stream>>>(src, tgt, pos, esrc, e);
    convert_w4<<<256, 256, 0, stream>>>(W1rel, W1root, W2rel, W2root, wb);  // after fill: pos dead
    convert_f32_bf16<<<(n * DD / 8 + 255) / 256, 256, 0, stream>>>(x, xb, n * DD / 8);

    // layer 1: gather x -> aggb; gemm writes bf16 h in-place into aggb
    gather_agg_bf16<<<(n + 3) / 4, 256, 0, stream>>>(xb, off, esrc, aggb, n);
    gemm_mfma<true><<<(n + 63) / 64, 256, 0, stream>>>(aggb, xb, wb, wb + 16384, b1, aggb, n);

    // layer 2: gather h -> xb (agg2); gemm writes fp32 to d_out
    gather_agg_bf16<<<(n + 3) / 4, 256, 0, stream>>>(aggb, off, esrc, xb, n);
    gemm_mfma<false><<<(n + 63) / 64, 256, 0, stream>>>(xb, aggb, wb + 32768, wb + 49152, b2, out, n);
}

// Round 6
// 178.595 us; speedup vs baseline: 2.9432x; 1.1322x over previous
//
#include <hip/hip_runtime.h>
#include <hip/hip_bf16.h>

#define DD 128

typedef __attribute__((ext_vector_type(8))) short bf16x8;
typedef __attribute__((ext_vector_type(4))) float f32x4;
typedef __attribute__((ext_vector_type(4))) unsigned short us4;
typedef unsigned short ushort_t;
typedef unsigned int uint_t;

__device__ inline ushort_t f2bf(float f) {
    __hip_bfloat16 h = __float2bfloat16(f);
    union { __hip_bfloat16 h; ushort_t u; } cv;
    cv.h = h;
    return cv.u;
}
__device__ inline float bf2f(uint_t lo16) {
    union { uint_t i; float f; } v;
    v.i = lo16 << 16;
    return v.f;
}

// ---------------- CSR build (single atomic pass) ----------------

__global__ __launch_bounds__(256) void zero_pos(int* __restrict__ p, int n4) {
    int i = blockIdx.x * 256 + threadIdx.x;
    if (i < n4) ((int4*)p)[i] = make_int4(0, 0, 0, 0);
}

// pass 1: the only atomic pass. pos[t] ends as degree(t); erank[j] = rank of edge j
// within its target bucket (assignment order nondeterministic; bucket SET is fixed).
__global__ __launch_bounds__(256) void count_rank(const int* __restrict__ tgt,
                                                  int* __restrict__ pos,
                                                  ushort_t* __restrict__ erank, int e) {
    int i = blockIdx.x * 256 + threadIdx.x;
    int e4 = e >> 2;
    if (i < e4) {
        int4 t = ((const int4*)tgt)[i];
        us4 r;
        r[0] = (ushort_t)atomicAdd(&pos[t.x], 1);
        r[1] = (ushort_t)atomicAdd(&pos[t.y], 1);
        r[2] = (ushort_t)atomicAdd(&pos[t.z], 1);
        r[3] = (ushort_t)atomicAdd(&pos[t.w], 1);
        ((us4*)erank)[i] = r;
    }
    if (i == 0)
        for (int j = e4 * 4; j < e; ++j)
            erank[j] = (ushort_t)atomicAdd(&pos[tgt[j]], 1);
}

// phase 1: per-block exclusive scan; off[i] = local excl prefix, bsum[b] = block total
__global__ __launch_bounds__(1024) void scan_part(const int* __restrict__ cnt,
                                                  int* __restrict__ off,
                                                  int* __restrict__ bsum, int n) {
    const int t = threadIdx.x;
    const int i = blockIdx.x * 1024 + t;
    const int v = (i < n) ? cnt[i] : 0;
    const int lane = t & 63, wv = t >> 6;
    int s = v;
#pragma unroll
    for (int d = 1; d < 64; d <<= 1) {
        int o = __shfl_up(s, d, 64);
        if (lane >= d) s += o;
    }
    __shared__ int wsum[16];
    if (lane == 63) wsum[wv] = s;
    __syncthreads();
    int woff = 0;
    for (int k = 0; k < wv; ++k) woff += wsum[k];
    if (i < n) off[i] = woff + s - v;           // local exclusive prefix
    if (t == 1023) bsum[blockIdx.x] = woff + s; // block total
}

// phase 2: one wave scans block totals in place (exclusive); off[n] = grand total
__global__ __launch_bounds__(64) void scan_bsum(int* __restrict__ bsum, int* __restrict__ off,
                                                int nb, int n) {
    const int t = threadIdx.x;
    const int v = (t < nb) ? bsum[t] : 0;
    int s = v;
#pragma unroll
    for (int d = 1; d < 64; d <<= 1) {
        int o = __shfl_up(s, d, 64);
        if (t >= d) s += o;
    }
    if (t < nb) bsum[t] = s - v;   // exclusive
    if (t == 63) off[n] = s;       // grand total (= e)
}

// phase 3: add block offsets into off
__global__ __launch_bounds__(1024) void scan_final(int* __restrict__ off,
                                                   const int* __restrict__ bsum, int n) {
    const int i = blockIdx.x * 1024 + threadIdx.x;
    if (i < n) off[i] += bsum[blockIdx.x];
}

// pass 2: atomic-free scatter. slot = off[tgt] + erank -> bijective over [0,e).
__global__ __launch_bounds__(256) void fill_scatter(const int* __restrict__ src,
                                                    const int* __restrict__ tgt,
                                                    const int* __restrict__ off,
                                                    const ushort_t* __restrict__ erank,
                                                    ushort_t* __restrict__ esrc, int e) {
    int i = blockIdx.x * 256 + threadIdx.x;
    int e4 = e >> 2;
    if (i < e4) {
        int4 t = ((const int4*)tgt)[i];
        int4 s = ((const int4*)src)[i];
        us4 r = ((const us4*)erank)[i];
        int o0 = off[t.x];
        int o1 = off[t.y];
        int o2 = off[t.z];
        int o3 = off[t.w];
        esrc[o0 + r[0]] = (ushort_t)s.x;
        esrc[o1 + r[1]] = (ushort_t)s.y;
        esrc[o2 + r[2]] = (ushort_t)s.z;
        esrc[o3 + r[3]] = (ushort_t)s.w;
    }
    if (i == 0)
        for (int j = e4 * 4; j < e; ++j)
            esrc[off[tgt[j]] + erank[j]] = (ushort_t)src[j];
}

// ---------------- fused conversion: x (n*128 f32) + 4 weight matrices ----------------

__global__ __launch_bounds__(256) void convert_all(const float* __restrict__ x,
                                                   ushort_t* __restrict__ xb,
                                                   const float* __restrict__ a,
                                                   const float* __restrict__ b,
                                                   const float* __restrict__ c,
                                                   const float* __restrict__ d,
                                                   ushort_t* __restrict__ wb, int n8) {
    int i = blockIdx.x * 256 + threadIdx.x;
    const float* in;
    ushort_t* outp;
    if (i < n8) {
        in = x + (size_t)i * 8;
        outp = xb + (size_t)i * 8;
    } else {
        int k = i - n8;              // weight chunk: 4 x 16384 elems = 8192 chunks
        if (k >= 8192) return;
        const float* p = (k < 2048) ? a : (k < 4096) ? b : (k < 6144) ? c : d;
        in = p + (size_t)(k & 2047) * 8;
        outp = wb + (size_t)k * 8;
    }
    const float4 va = *(const float4*)in;
    const float4 vb = *(const float4*)(in + 4);
    ushort_t r[8];
    r[0] = f2bf(va.x); r[1] = f2bf(va.y); r[2] = f2bf(va.z); r[3] = f2bf(va.w);
    r[4] = f2bf(vb.x); r[5] = f2bf(vb.y); r[6] = f2bf(vb.z); r[7] = f2bf(vb.w);
    *(bf16x8*)outp = *(bf16x8*)r;
}

// ---------------- gather-aggregate (one wave per node, bf16 rows) ----------------
// K-deep software batch: K independent id loads (same cache line), then K
// independent 256B row loads in flight, one waitcnt per batch -> MLP = K.

template<int K>
__device__ inline void gath(const ushort_t* __restrict__ xrow,
                            const ushort_t* __restrict__ esrc, int j,
                            float& ax, float& ay) {
    int s[K];
    uint_t v[K];
#pragma unroll
    for (int k = 0; k < K; ++k) s[k] = esrc[j + k];
#pragma unroll
    for (int k = 0; k < K; ++k) v[k] = *(const uint_t*)(xrow + (size_t)s[k] * DD);
#pragma unroll
    for (int k = 0; k < K; ++k) {
        ax += bf2f(v[k] & 0xffffu);
        ay += bf2f(v[k] >> 16);
    }
}

__global__ __launch_bounds__(256) void gather_agg_bf16(const ushort_t* __restrict__ xin,
                                                       const int* __restrict__ off,
                                                       const ushort_t* __restrict__ esrc,
                                                       ushort_t* __restrict__ agg, int n) {
    const int lane = threadIdx.x & 63;
    const int node = blockIdx.x * 4 + (threadIdx.x >> 6);
    if (node >= n) return;
    const int beg = off[node], end = off[node + 1];
    const ushort_t* xrow = xin + lane * 2;
    float ax = 0.f, ay = 0.f;
    int j = beg;
    for (; j + 8 <= end; j += 8) gath<8>(xrow, esrc, j, ax, ay);
    if (j + 4 <= end) { gath<4>(xrow, esrc, j, ax, ay); j += 4; }
    if (j + 2 <= end) { gath<2>(xrow, esrc, j, ax, ay); j += 2; }
    if (j < end)      { gath<1>(xrow, esrc, j, ax, ay); }
    uint_t r = ((uint_t)f2bf(ay) << 16) | (uint_t)f2bf(ax);
    *(uint_t*)(agg + (size_t)node * DD + lane * 2) = r;
}

// ---------------- MFMA dual-GEMM + bias + relu ----------------
// out = relu(Aagg @ Wrel^T + Aroot @ Wroot^T + bias)
// A fragment: lane holds A[rbase + (lane&15)][8*(lane>>4) + k0 .. +7]  (16B contiguous)
// B fragment: lane holds W[j*16 + (lane&15)][8*(lane>>4) + k0 .. +7]   (W is [n][k] row-major = B^T)
// D: row = (lane>>4)*4 + i, col = j*16 + (lane&15)
// In-place safe when outv == Aagg: rows are wave-disjoint; all loads' data are
// consumed (waitcnt) before any store issues.
template<bool OUT_BF16>
__global__ __launch_bounds__(256) void gemm_mfma(
    const ushort_t* Aagg, const ushort_t* __restrict__ Aroot,
    const ushort_t* __restrict__ Wrel, const ushort_t* __restrict__ Wroot,
    const float* __restrict__ bias, void* outv, int n)
{
    const int wave = threadIdx.x >> 6;
    const int lane = threadIdx.x & 63;
    const int m = lane & 15;
    const int kg = lane >> 4;
    const int rbase = blockIdx.x * 64 + wave * 16;
    if (rbase >= n) return;               // n % 16 == 0: active waves fully valid
    const size_t aoff = (size_t)(rbase + m) * DD + kg * 8;

    f32x4 acc[8];
#pragma unroll
    for (int j = 0; j < 8; ++j) acc[j] = (f32x4){0.f, 0.f, 0.f, 0.f};

#pragma unroll
    for (int k0 = 0; k0 < DD; k0 += 32) {
        bf16x8 aA = *(const bf16x8*)(Aagg + aoff + k0);
        bf16x8 aR = *(const bf16x8*)(Aroot + aoff + k0);
#pragma unroll
        for (int j = 0; j < 8; ++j) {
            bf16x8 bL = *(const bf16x8*)(Wrel + (size_t)(j * 16 + m) * DD + kg * 8 + k0);
            bf16x8 bR = *(const bf16x8*)(Wroot + (size_t)(j * 16 + m) * DD + kg * 8 + k0);
            acc[j] = __builtin_amdgcn_mfma_f32_16x16x32_bf16(aA, bL, acc[j], 0, 0, 0);
            acc[j] = __builtin_amdgcn_mfma_f32_16x16x32_bf16(aR, bR, acc[j], 0, 0, 0);
        }
    }

    const int orow = rbase + kg * 4;
#pragma unroll
    for (int j = 0; j < 8; ++j) {
        const int col = j * 16 + m;
        const float bv = bias[col];
#pragma unroll
        for (int i = 0; i < 4; ++i) {
            float v = acc[j][i] + bv;
            v = v > 0.f ? v : 0.f;
            if (OUT_BF16)
                ((ushort_t*)outv)[(size_t)(orow + i) * DD + col] = f2bf(v);
            else
                ((float*)outv)[(size_t)(orow + i) * DD + col] = v;
        }
    }
}

extern "C" void kernel_launch(void* const* d_in, const int* in_sizes, int n_in,
                              void* d_out, int out_size, void* d_ws, size_t ws_size,
                              hipStream_t stream) {
    const float* x = (const float*)d_in[0];
    const int* ei = (const int*)d_in[1];
    const float* W1rel = (const float*)d_in[2];
    const float* b1 = (const float*)d_in[3];
    const float* W1root = (const float*)d_in[4];
    const float* W2rel = (const float*)d_in[5];
    const float* b2 = (const float*)d_in[6];
    const float* W2root = (const float*)d_in[7];
    float* out = (float*)d_out;

    const int n = in_sizes[0] / DD;        // 50000
    const int e = in_sizes[1] / 2;         // 600000
    const int* src = ei;
    const int* tgt = ei + e;
    const int nb = (n + 1023) / 1024;      // 49 scan blocks

    // workspace layout (~28.4 MB)
    char* ws = (char*)d_ws;
    int* off  = (int*)ws;                        // (n+1) ints        [0, 200004)
    int* bsum = (int*)(ws + 200064);             // 64 ints
    int* pos  = (int*)(ws + 200320);             // n ints (degrees), dead after scan_part
    ushort_t* wb = (ushort_t*)(ws + 200320);     // 4x16384 bf16 weights, reuses pos
    ushort_t* esrc = (ushort_t*)(ws + 400384);   // e ushorts (1.2MB)
    ushort_t* erank = (ushort_t*)(ws + 1600384); // e ushorts (1.2MB)
    ushort_t* aggb = (ushort_t*)(ws + 2800640);  // n*128 bf16: agg1, then h (in-place)
    ushort_t* xb = (ushort_t*)(ws + 15600640);   // n*128 bf16: x, then agg2

    zero_pos<<<(n / 4 + 255) / 256, 256, 0, stream>>>(pos, n / 4);
    count_rank<<<(e / 4 + 255) / 256, 256, 0, stream>>>(tgt, pos, erank, e);
    scan_part<<<nb, 1024, 0, stream>>>(pos, off, bsum, n);
    scan_bsum<<<1, 64, 0, stream>>>(bsum, off, nb, n);
    scan_final<<<nb, 1024, 0, stream>>>(off, bsum, n);
    fill_scatter<<<(e / 4 + 255) / 256, 256, 0, stream>>>(src, tgt, off, erank, esrc, e);
    // after scan_part, pos (degrees) is dead -> wb reuses it
    convert_all<<<(n * DD / 8 + 8192 + 255) / 256, 256, 0, stream>>>(
        x, xb, W1rel, W1root, W2rel, W2root, wb, n * DD / 8);

    // layer 1: gather x -> aggb; gemm writes bf16 h in-place into aggb
    gather_agg_bf16<<<(n + 3) / 4, 256, 0, stream>>>(xb, off, esrc, aggb, n);
    gemm_mfma<true><<<(n + 63) / 64, 256, 0, stream>>>(aggb, xb, wb, wb + 16384, b1, aggb, n);

    // layer 2: gather h -> xb (agg2); gemm writes fp32 to d_out
    gather_agg_bf16<<<(n + 3) / 4, 256, 0, stream>>>(aggb, off, esrc, xb, n);
    gemm_mfma<false><<<(n + 63) / 64, 256, 0, stream>>>(xb, aggb, wb + 32768, wb + 49152, b2, out, n);
}

// Round 7
// 174.952 us; speedup vs baseline: 3.0045x; 1.0208x over previous
//
#include <hip/hip_runtime.h>
#include <hip/hip_bf16.h>

#define DD 128

typedef __attribute__((ext_vector_type(8))) short bf16x8;
typedef __attribute__((ext_vector_type(4))) float f32x4;
typedef __attribute__((ext_vector_type(8))) unsigned short us8;
typedef unsigned short ushort_t;
typedef unsigned int uint_t;

__device__ inline ushort_t f2bf(float f) {
    __hip_bfloat16 h = __float2bfloat16(f);
    union { __hip_bfloat16 h; ushort_t u; } cv;
    cv.h = h;
    return cv.u;
}
__device__ inline float bf2f(uint_t lo16) {
    union { uint_t i; float f; } v;
    v.i = lo16 << 16;
    return v.f;
}
__device__ inline void conv8(const float* __restrict__ in, ushort_t* __restrict__ outp) {
    const float4 va = *(const float4*)in;
    const float4 vb = *(const float4*)(in + 4);
    ushort_t r[8];
    r[0] = f2bf(va.x); r[1] = f2bf(va.y); r[2] = f2bf(va.z); r[3] = f2bf(va.w);
    r[4] = f2bf(vb.x); r[5] = f2bf(vb.y); r[6] = f2bf(vb.z); r[7] = f2bf(vb.w);
    *(bf16x8*)outp = *(bf16x8*)r;
}

// ---------------- kernel 1: zero pos  ||  convert x -> bf16 ----------------

__global__ __launch_bounds__(256) void zero_convx(int* __restrict__ pos, int n4, int zb,
                                                  const float* __restrict__ x,
                                                  ushort_t* __restrict__ xb, int n8) {
    if ((int)blockIdx.x < zb) {
        int i = blockIdx.x * 256 + threadIdx.x;
        if (i < n4) ((int4*)pos)[i] = make_int4(0, 0, 0, 0);
    } else {
        int i = (blockIdx.x - zb) * 256 + threadIdx.x;
        if (i < n8) conv8(x + (size_t)i * 8, xb + (size_t)i * 8);
    }
}

// ---------------- kernel 2: single atomic pass (8 edges/thread) ----------------
// pos[t] ends as degree(t); erank[j] = rank of edge j within its target bucket.

__global__ __launch_bounds__(256) void count_rank(const int* __restrict__ tgt,
                                                  int* __restrict__ pos,
                                                  ushort_t* __restrict__ erank, int e) {
    int i = blockIdx.x * 256 + threadIdx.x;
    int e8 = e >> 3;
    if (i < e8) {
        int4 t0 = ((const int4*)tgt)[i * 2];
        int4 t1 = ((const int4*)tgt)[i * 2 + 1];
        us8 r;
        r[0] = (ushort_t)atomicAdd(&pos[t0.x], 1);
        r[1] = (ushort_t)atomicAdd(&pos[t0.y], 1);
        r[2] = (ushort_t)atomicAdd(&pos[t0.z], 1);
        r[3] = (ushort_t)atomicAdd(&pos[t0.w], 1);
        r[4] = (ushort_t)atomicAdd(&pos[t1.x], 1);
        r[5] = (ushort_t)atomicAdd(&pos[t1.y], 1);
        r[6] = (ushort_t)atomicAdd(&pos[t1.z], 1);
        r[7] = (ushort_t)atomicAdd(&pos[t1.w], 1);
        ((us8*)erank)[i] = r;
    }
    if (i == 0)
        for (int j = e8 * 8; j < e; ++j)
            erank[j] = (ushort_t)atomicAdd(&pos[tgt[j]], 1);
}

// ---------------- kernel 3: per-block exclusive scan ----------------

__global__ __launch_bounds__(1024) void scan_part(const int* __restrict__ cnt,
                                                  int* __restrict__ off,
                                                  int* __restrict__ bsum, int n) {
    const int t = threadIdx.x;
    const int i = blockIdx.x * 1024 + t;
    const int v = (i < n) ? cnt[i] : 0;
    const int lane = t & 63, wv = t >> 6;
    int s = v;
#pragma unroll
    for (int d = 1; d < 64; d <<= 1) {
        int o = __shfl_up(s, d, 64);
        if (lane >= d) s += o;
    }
    __shared__ int wsum[16];
    if (lane == 63) wsum[wv] = s;
    __syncthreads();
    int woff = 0;
    for (int k = 0; k < wv; ++k) woff += wsum[k];
    if (i < n) off[i] = woff + s - v;           // local exclusive prefix
    if (t == 1023) bsum[blockIdx.x] = woff + s; // raw block total
}

// ---------------- kernel 4: add block offsets (inline bsum re-scan)  ||  convert W ----------------
// pos (aliased by wb) is dead after scan_part -> safe to write wb here.

__global__ __launch_bounds__(1024) void scan_final_convw(int* __restrict__ off,
                                                         const int* __restrict__ bsum,
                                                         int n, int nb,
                                                         const float* __restrict__ a,
                                                         const float* __restrict__ b,
                                                         const float* __restrict__ c,
                                                         const float* __restrict__ d,
                                                         ushort_t* __restrict__ wb) {
    const int blk = blockIdx.x;
    if (blk < nb) {
        int pre = 0;
        for (int k = 0; k < blk; ++k) pre += bsum[k];   // 49 L2-cached broadcast loads
        const int i = blk * 1024 + threadIdx.x;
        if (i < n) off[i] += pre;
        if (blk == nb - 1 && threadIdx.x == 0) {
            int tot = pre;
            for (int k = blk; k < nb; ++k) tot += bsum[k];
            off[n] = tot;                                // grand total (= e)
        }
    } else {
        int k = (blk - nb) * 1024 + threadIdx.x;         // 8192 weight chunks of 8
        if (k >= 8192) return;
        const float* p = (k < 2048) ? a : (k < 4096) ? b : (k < 6144) ? c : d;
        conv8(p + (size_t)(k & 2047) * 8, wb + (size_t)k * 8);
    }
}

// ---------------- kernel 5: atomic-free scatter (8 edges/thread) ----------------

__global__ __launch_bounds__(256) void fill_scatter(const int* __restrict__ src,
                                                    const int* __restrict__ tgt,
                                                    const int* __restrict__ off,
                                                    const ushort_t* __restrict__ erank,
                                                    ushort_t* __restrict__ esrc, int e) {
    int i = blockIdx.x * 256 + threadIdx.x;
    int e8 = e >> 3;
    if (i < e8) {
        int4 t0 = ((const int4*)tgt)[i * 2];
        int4 t1 = ((const int4*)tgt)[i * 2 + 1];
        int4 s0 = ((const int4*)src)[i * 2];
        int4 s1 = ((const int4*)src)[i * 2 + 1];
        us8 r = ((const us8*)erank)[i];
        int o0 = off[t0.x], o1 = off[t0.y], o2 = off[t0.z], o3 = off[t0.w];
        int o4 = off[t1.x], o5 = off[t1.y], o6 = off[t1.z], o7 = off[t1.w];
        esrc[o0 + r[0]] = (ushort_t)s0.x;
        esrc[o1 + r[1]] = (ushort_t)s0.y;
        esrc[o2 + r[2]] = (ushort_t)s0.z;
        esrc[o3 + r[3]] = (ushort_t)s0.w;
        esrc[o4 + r[4]] = (ushort_t)s1.x;
        esrc[o5 + r[5]] = (ushort_t)s1.y;
        esrc[o6 + r[6]] = (ushort_t)s1.z;
        esrc[o7 + r[7]] = (ushort_t)s1.w;
    }
    if (i == 0)
        for (int j = e8 * 8; j < e; ++j)
            esrc[off[tgt[j]] + erank[j]] = (ushort_t)src[j];
}

// ---------------- gather-aggregate (one wave per node, bf16 rows) ----------------
// K-deep software batch: K independent id loads (same cache line), then K
// independent 256B row loads in flight, one waitcnt per batch -> MLP = K.

template<int K>
__device__ inline void gath(const ushort_t* __restrict__ xrow,
                            const ushort_t* __restrict__ esrc, int j,
                            float& ax, float& ay) {
    int s[K];
    uint_t v[K];
#pragma unroll
    for (int k = 0; k < K; ++k) s[k] = esrc[j + k];
#pragma unroll
    for (int k = 0; k < K; ++k) v[k] = *(const uint_t*)(xrow + (size_t)s[k] * DD);
#pragma unroll
    for (int k = 0; k < K; ++k) {
        ax += bf2f(v[k] & 0xffffu);
        ay += bf2f(v[k] >> 16);
    }
}

__global__ __launch_bounds__(256) void gather_agg_bf16(const ushort_t* __restrict__ xin,
                                                       const int* __restrict__ off,
                                                       const ushort_t* __restrict__ esrc,
                                                       ushort_t* __restrict__ agg, int n) {
    const int lane = threadIdx.x & 63;
    const int node = blockIdx.x * 4 + (threadIdx.x >> 6);
    if (node >= n) return;
    const int beg = off[node], end = off[node + 1];
    const ushort_t* xrow = xin + lane * 2;
    float ax = 0.f, ay = 0.f;
    int j = beg;
    for (; j + 8 <= end; j += 8) gath<8>(xrow, esrc, j, ax, ay);
    if (j + 4 <= end) { gath<4>(xrow, esrc, j, ax, ay); j += 4; }
    if (j + 2 <= end) { gath<2>(xrow, esrc, j, ax, ay); j += 2; }
    if (j < end)      { gath<1>(xrow, esrc, j, ax, ay); }
    uint_t r = ((uint_t)f2bf(ay) << 16) | (uint_t)f2bf(ax);
    *(uint_t*)(agg + (size_t)node * DD + lane * 2) = r;
}

// ---------------- MFMA dual-GEMM + bias + relu ----------------
// out = relu(Aagg @ Wrel^T + Aroot @ Wroot^T + bias)
// A fragment: lane holds A[rbase + (lane&15)][8*(lane>>4) + k0 .. +7]  (16B contiguous)
// B fragment: lane holds W[j*16 + (lane&15)][8*(lane>>4) + k0 .. +7]   (W is [n][k] row-major = B^T)
// D: row = (lane>>4)*4 + i, col = j*16 + (lane&15)
// In-place safe when outv == Aagg: rows are wave-disjoint; all loads' data are
// consumed (waitcnt) before any store issues.
template<bool OUT_BF16>
__global__ __launch_bounds__(256) void gemm_mfma(
    const ushort_t* Aagg, const ushort_t* __restrict__ Aroot,
    const ushort_t* __restrict__ Wrel, const ushort_t* __restrict__ Wroot,
    const float* __restrict__ bias, void* outv, int n)
{
    const int wave = threadIdx.x >> 6;
    const int lane = threadIdx.x & 63;
    const int m = lane & 15;
    const int kg = lane >> 4;
    const int rbase = blockIdx.x * 64 + wave * 16;
    if (rbase >= n) return;               // n % 16 == 0: active waves fully valid
    const size_t aoff = (size_t)(rbase + m) * DD + kg * 8;

    f32x4 acc[8];
#pragma unroll
    for (int j = 0; j < 8; ++j) acc[j] = (f32x4){0.f, 0.f, 0.f, 0.f};

#pragma unroll
    for (int k0 = 0; k0 < DD; k0 += 32) {
        bf16x8 aA = *(const bf16x8*)(Aagg + aoff + k0);
        bf16x8 aR = *(const bf16x8*)(Aroot + aoff + k0);
#pragma unroll
        for (int j = 0; j < 8; ++j) {
            bf16x8 bL = *(const bf16x8*)(Wrel + (size_t)(j * 16 + m) * DD + kg * 8 + k0);
            bf16x8 bR = *(const bf16x8*)(Wroot + (size_t)(j * 16 + m) * DD + kg * 8 + k0);
            acc[j] = __builtin_amdgcn_mfma_f32_16x16x32_bf16(aA, bL, acc[j], 0, 0, 0);
            acc[j] = __builtin_amdgcn_mfma_f32_16x16x32_bf16(aR, bR, acc[j], 0, 0, 0);
        }
    }

    const int orow = rbase + kg * 4;
#pragma unroll
    for (int j = 0; j < 8; ++j) {
        const int col = j * 16 + m;
        const float bv = bias[col];
#pragma unroll
        for (int i = 0; i < 4; ++i) {
            float v = acc[j][i] + bv;
            v = v > 0.f ? v : 0.f;
            if (OUT_BF16)
                ((ushort_t*)outv)[(size_t)(orow + i) * DD + col] = f2bf(v);
            else
                ((float*)outv)[(size_t)(orow + i) * DD + col] = v;
        }
    }
}

extern "C" void kernel_launch(void* const* d_in, const int* in_sizes, int n_in,
                              void* d_out, int out_size, void* d_ws, size_t ws_size,
                              hipStream_t stream) {
    const float* x = (const float*)d_in[0];
    const int* ei = (const int*)d_in[1];
    const float* W1rel = (const float*)d_in[2];
    const float* b1 = (const float*)d_in[3];
    const float* W1root = (const float*)d_in[4];
    const float* W2rel = (const float*)d_in[5];
    const float* b2 = (const float*)d_in[6];
    const float* W2root = (const float*)d_in[7];
    float* out = (float*)d_out;

    const int n = in_sizes[0] / DD;        // 50000
    const int e = in_sizes[1] / 2;         // 600000
    const int* src = ei;
    const int* tgt = ei + e;
    const int nb = (n + 1023) / 1024;      // 49 scan blocks
    const int n8 = n * DD / 8;             // 800000 x-chunks
    const int zb = (n / 4 + 255) / 256;    // 49 zero blocks

    // workspace layout (~28.4 MB)
    char* ws = (char*)d_ws;
    int* off  = (int*)ws;                        // (n+1) ints        [0, 200004)
    int* bsum = (int*)(ws + 200064);             // 64 ints
    int* pos  = (int*)(ws + 200320);             // n ints (degrees), dead after scan_part
    ushort_t* wb = (ushort_t*)(ws + 200320);     // 4x16384 bf16 weights, reuses pos
    ushort_t* esrc = (ushort_t*)(ws + 400384);   // e ushorts (1.2MB)
    ushort_t* erank = (ushort_t*)(ws + 1600384); // e ushorts (1.2MB)
    ushort_t* aggb = (ushort_t*)(ws + 2800640);  // n*128 bf16: agg1, then h (in-place)
    ushort_t* xb = (ushort_t*)(ws + 15600640);   // n*128 bf16: x, then agg2

    // 1: zero pos || convert x
    zero_convx<<<zb + (n8 + 255) / 256, 256, 0, stream>>>(pos, n / 4, zb, x, xb, n8);
    // 2: atomic pass
    count_rank<<<(e / 8 + 255) / 256, 256, 0, stream>>>(tgt, pos, erank, e);
    // 3-4: scan (+ weight convert piggybacked on 4)
    scan_part<<<nb, 1024, 0, stream>>>(pos, off, bsum, n);
    scan_final_convw<<<nb + 8, 1024, 0, stream>>>(off, bsum, n, nb,
                                                  W1rel, W1root, W2rel, W2root, wb);
    // 5: atomic-free scatter
    fill_scatter<<<(e / 8 + 255) / 256, 256, 0, stream>>>(src, tgt, off, erank, esrc, e);

    // layer 1: gather x -> aggb; gemm writes bf16 h in-place into aggb
    gather_agg_bf16<<<(n + 3) / 4, 256, 0, stream>>>(xb, off, esrc, aggb, n);
    gemm_mfma<true><<<(n + 63) / 64, 256, 0, stream>>>(aggb, xb, wb, wb + 16384, b1, aggb, n);

    // layer 2: gather h -> xb (agg2); gemm writes fp32 to d_out
    gather_agg_bf16<<<(n + 3) / 4, 256, 0, stream>>>(aggb, off, esrc, xb, n);
    gemm_mfma<false><<<(n + 63) / 64, 256, 0, stream>>>(xb, aggb, wb + 32768, wb + 49152, b2, out, n);
}